// Round 10
// baseline (415.475 us; speedup 1.0000x reference)
//
#include <hip/hip_runtime.h>

#define HD 128
#define NN 50000
#define NE 600000
#define EPW 16            // edges per wave (wave-autonomous)
#define EPB 64            // 4 waves x 16 edges
#define NPB 32            // nodes per block (node kernel)
#define XST 296           // per-wave X row stride (bf16)
#define TST 136           // T/M row stride (bf16)
#define MOFF 2304         // M offset within wave slice (entries): [2304,4480) fits 4736
#define K1P 288           // padded K for edge layer1
#define NXST 264          // node X LDS row stride (bf16)
#define NB_E (NE / EPB)   // 9375
#define NB_N ((NN + NPB - 1) / NPB)

typedef __attribute__((ext_vector_type(8))) short short8v;
typedef __attribute__((ext_vector_type(4))) short short4v;
typedef __attribute__((ext_vector_type(4))) float f32x4;

#define MFMA_BF16(a, b, c) __builtin_amdgcn_mfma_f32_16x16x32_bf16(a, b, c, 0, 0, 0)

__device__ __forceinline__ float silu(float x) {
    return x / (1.0f + __expf(-x));
}
__device__ __forceinline__ unsigned short f2bf(float x) {   // RNE f32 -> bf16
    unsigned u = __float_as_uint(x);
    unsigned r = (u + 0x7FFFu + ((u >> 16) & 1u)) >> 16;
    return (unsigned short)r;
}
__device__ __forceinline__ float bf2f(unsigned short u) {
    return __uint_as_float((unsigned)u << 16);
}
__device__ __forceinline__ void atomic_pk_bf16(unsigned short* dst, unsigned pk) {
    asm volatile("global_atomic_pk_add_bf16 %0, %1, off" :: "v"(dst), "v"(pk) : "memory");
}

// ---- prep: transpose+convert weights to bf16 in ws ----
// layout: w1t[128][288] | w2t[128][128] | n1t[128][256] | n2t[128][128] | cw1p[16][128]
#define W1T_N (128 * K1P)
#define W2T_N (128 * 128)
#define N1T_N (128 * 256)
#define N2T_N (128 * 128)
#define C1P_N (16 * 128)
#define WTOT  (W1T_N + W2T_N + N1T_N + N2T_N + C1P_N)

__global__ __launch_bounds__(256) void prep_weights(
    const float* __restrict__ mw1, const float* __restrict__ mw2,
    const float* __restrict__ nw1, const float* __restrict__ nw2,
    const float* __restrict__ cw1, unsigned short* __restrict__ wt)
{
    int idx = blockIdx.x * 256 + threadIdx.x;
    if (idx < W1T_N) {
        int c = idx / K1P, k = idx % K1P;
        wt[idx] = (k < 257) ? f2bf(mw1[(size_t)k * HD + c]) : (unsigned short)0;
    } else if (idx < W1T_N + W2T_N) {
        int i = idx - W1T_N;
        int c = i / 128, k = i % 128;
        wt[idx] = f2bf(mw2[(size_t)k * HD + c]);
    } else if (idx < W1T_N + W2T_N + N1T_N) {
        int i = idx - (W1T_N + W2T_N);
        int c = i / 256, k = i % 256;
        wt[idx] = f2bf(nw1[(size_t)k * HD + c]);
    } else if (idx < W1T_N + W2T_N + N1T_N + N2T_N) {
        int i = idx - (W1T_N + W2T_N + N1T_N);
        int c = i / 128, k = i % 128;
        wt[idx] = f2bf(nw2[(size_t)k * HD + c]);
    } else if (idx < WTOT) {
        int i = idx - (W1T_N + W2T_N + N1T_N + N2T_N);
        int n = i / 128, k = i % 128;
        wt[idx] = (n < 4) ? f2bf(cw1[(size_t)k * 4 + n]) : (unsigned short)0;
    }
}

__global__ __launch_bounds__(256) void prep_h(
    const float* __restrict__ h, unsigned short* __restrict__ hb)
{
    size_t idx = (size_t)(blockIdx.x * 256 + threadIdx.x) * 4;
    float4 f = *reinterpret_cast<const float4*>(h + idx);
    short4v v;
    v[0] = (short)f2bf(f.x); v[1] = (short)f2bf(f.y);
    v[2] = (short)f2bf(f.z); v[3] = (short)f2bf(f.w);
    *reinterpret_cast<short4v*>(hb + idx) = v;
}

// ============ edge kernel: wave-autonomous, ZERO barriers ============
// Each wave owns 16 edges end-to-end in its private LDS slice of 4736 entries:
//   X[16][296] bf16; T aliases entries [0, 2176); M at [2304, 4480).
// Wave-serial program order makes the aliasing safe (all X reads precede
// T writes; all T reads precede nothing that conflicts; M disjoint from T).
// All atomics issue at the very end -> true fire-and-forget.
// MODE 2: bf16 gather + pk-bf16 atomics. MODE 0: f32 gather + f32 atomics.
template <int MODE>
__global__ __launch_bounds__(256, 4) void egnn_edge_wa(
    const float* __restrict__ h, const unsigned short* __restrict__ hb,
    const float* __restrict__ pos, const int* __restrict__ ei,
    const unsigned short* __restrict__ w1t, const float* __restrict__ mb1,
    const unsigned short* __restrict__ w2t, const float* __restrict__ mb2,
    const unsigned short* __restrict__ cw1p, const float* __restrict__ cb1,
    const float* __restrict__ cw2, const float* __restrict__ cb2,
    float* __restrict__ agg_f32, unsigned short* __restrict__ agg_bf,
    float* __restrict__ agg_trans)
{
    __shared__ __align__(16) unsigned short X4[4 * EPW * XST];
    __shared__ int rows4[EPB];
    __shared__ float cd4[EPB][3];

    const int tid  = threadIdx.x;
    const int lane = tid & 63;
    const int w    = tid >> 6;
    const int lr   = lane & 15;
    const int lkq  = lane >> 4;
    const int lk   = lkq * 8;
    unsigned short* Xw = X4 + w * EPW * XST;
    int*   rows = rows4 + w * EPW;
    float (*cd)[3] = cd4 + w * EPW;
    const int e0 = blockIdx.x * EPB + w * EPW;

    // ---- meta: indices, coord diff, radial (lane<16; wave-private) ----
    if (lane < EPW) {
        const int r = ei[e0 + lane];
        const int c = ei[(size_t)NE + e0 + lane];
        rows[lane] = r;
        const float d0 = pos[r * 3 + 0] - pos[c * 3 + 0];
        const float d1 = pos[r * 3 + 1] - pos[c * 3 + 1];
        const float d2 = pos[r * 3 + 2] - pos[c * 3 + 2];
        cd[lane][0] = d0; cd[lane][1] = d1; cd[lane][2] = d2;
        Xw[lane * XST + 256] = f2bf(d0 * d0 + d1 * d1 + d2 * d2 + 1e-8f);
    }
    // zero pad cols 257..287
    #pragma unroll
    for (int j = 0; j < 8; ++j) {
        const int idx = j * 64 + lane;          // 0..511
        const int e = idx >> 5, c = 257 + (idx & 31);
        if (c < 288) Xw[e * XST + c] = 0;
    }

    // ---- gather this wave's 32 rows (16 h_row + 16 h_col), 8 x 16B per lane ----
    #pragma unroll
    for (int p = 0; p < 8; ++p) {
        const int slot = p * 4 + lkq;           // 0..31
        const int e    = slot & 15;
        const int half = slot >> 4;
        const int src  = ei[(size_t)(half ? NE : 0) + e0 + e];
        short8v v;
        if (MODE >= 1) {
            v = *reinterpret_cast<const short8v*>(hb + (size_t)src * HD + (lane & 15) * 8);
        } else {
            const float* hp = h + (size_t)src * HD + (lane & 15) * 8;
            float4 f0 = *reinterpret_cast<const float4*>(hp);
            float4 f1 = *reinterpret_cast<const float4*>(hp + 4);
            v[0] = (short)f2bf(f0.x); v[1] = (short)f2bf(f0.y);
            v[2] = (short)f2bf(f0.z); v[3] = (short)f2bf(f0.w);
            v[4] = (short)f2bf(f1.x); v[5] = (short)f2bf(f1.y);
            v[6] = (short)f2bf(f1.z); v[7] = (short)f2bf(f1.w);
        }
        *reinterpret_cast<short8v*>(&Xw[e * XST + half * 128 + (lane & 15) * 8]) = v;
    }
    // no barrier: all consumers below are this wave's own LDS accesses (program-ordered)

    // ---- layer 1: X[16,288] @ W1T^T -> all 128 cols for this wave's 16 edges ----
    f32x4 acc1[8] = {};
    {
        __builtin_amdgcn_s_setprio(1);
        #pragma unroll
        for (int ks = 0; ks < 9; ++ks) {
            const int k0 = ks * 32;
            short8v a = *reinterpret_cast<const short8v*>(&Xw[lr * XST + lk + k0]);
            #pragma unroll
            for (int nt = 0; nt < 8; ++nt) {
                short8v b = *reinterpret_cast<const short8v*>(
                    w1t + (size_t)(nt * 16 + lr) * K1P + lk + k0);
                acc1[nt] = MFMA_BF16(a, b, acc1[nt]);
            }
        }
        __builtin_amdgcn_s_setprio(0);
    }

    // ---- silu -> T (aliases X entries [0,2176); X reads all program-order done) ----
    unsigned short* T = Xw;
    unsigned short* M = Xw + MOFF;
    #pragma unroll
    for (int nt = 0; nt < 8; ++nt) {
        const int n  = nt * 16 + lr;
        const float bb = mb1[n];
        #pragma unroll
        for (int r = 0; r < 4; ++r)
            T[(lkq * 4 + r) * TST + n] = f2bf(silu(acc1[nt][r] + bb));
    }

    // ---- layer 2: T[16,128] @ W2T^T -> msg (all 128 cols) ----
    f32x4 acc2[8] = {};
    {
        __builtin_amdgcn_s_setprio(1);
        #pragma unroll
        for (int ks = 0; ks < 4; ++ks) {
            const int k0 = ks * 32;
            short8v a = *reinterpret_cast<const short8v*>(&T[lr * TST + lk + k0]);
            #pragma unroll
            for (int nt = 0; nt < 8; ++nt) {
                short8v b = *reinterpret_cast<const short8v*>(
                    w2t + (size_t)(nt * 16 + lr) * 128 + lk + k0);
                acc2[nt] = MFMA_BF16(a, b, acc2[nt]);
            }
        }
        __builtin_amdgcn_s_setprio(0);
    }
    #pragma unroll
    for (int nt = 0; nt < 8; ++nt) {
        const int n  = nt * 16 + lr;
        const float bb = mb2[n];
        #pragma unroll
        for (int r = 0; r < 4; ++r)
            M[(lkq * 4 + r) * TST + n] = f2bf(acc2[nt][r] + bb);
    }

    // ---- coord MLP (before any atomic) ----
    {
        f32x4 accc = {};
        #pragma unroll
        for (int ks = 0; ks < 4; ++ks) {
            short8v b = *reinterpret_cast<const short8v*>(
                cw1p + (size_t)lr * 128 + lk + ks * 32);
            short8v a = *reinterpret_cast<const short8v*>(&M[lr * TST + lk + ks * 32]);
            accc = MFMA_BF16(a, b, accc);
        }
        const int q = lr;
        const float b1q = (q < 4) ? cb1[q] : 0.f;
        const float c2q = (q < 4) ? cw2[q] : 0.f;
        const float cb2v = cb2[0];
        #pragma unroll
        for (int r = 0; r < 4; ++r) {
            float tv = silu(accc[r] + b1q) * c2q;
            tv += __shfl_xor(tv, 1);
            tv += __shfl_xor(tv, 2);
            const float cwt = tv + cb2v;
            if (q < 3) {
                const int e = lkq * 4 + r;
                atomicAdd(&agg_trans[rows[e] * 3 + q], cd[e][q] * cwt);
            }
        }
    }

    // ---- msg scatter LAST: nothing vmem-dependent after these ----
    if (MODE == 2) {
        #pragma unroll
        for (int t = 0; t < 16; ++t) {
            const int idx = t * 64 + lane;      // 0..1023
            const int e   = idx >> 6;           // == t (wave-uniform)
            const int pc  = idx & 63;
            const unsigned pk = *reinterpret_cast<const unsigned*>(M + e * TST + pc * 2);
            atomic_pk_bf16(agg_bf + ((size_t)rows[e] * HD + pc * 2), pk);
        }
    } else {
        #pragma unroll
        for (int t = 0; t < 32; ++t) {
            const int idx = t * 64 + lane;      // 0..2047
            const int e   = idx >> 7;
            const int ch  = idx & 127;
            atomicAdd(&agg_f32[(size_t)rows[e] * HD + ch], bf2f(M[e * TST + ch]));
        }
    }
}

// ============ node kernel ============
template <int MODE>
__global__ __launch_bounds__(256, 6) void egnn_node_mfma(
    const float* __restrict__ h, const unsigned short* __restrict__ hb,
    const float* __restrict__ pos,
    const unsigned short* __restrict__ n1t, const float* __restrict__ nb1,
    const unsigned short* __restrict__ n2t, const float* __restrict__ nb2,
    const float* __restrict__ agg_f32, const unsigned short* __restrict__ agg_bf,
    float* __restrict__ out_h, float* __restrict__ out_pos)
{
    __shared__ __align__(16) unsigned short Xn[NPB * NXST];
    __shared__ __align__(16) unsigned short Tn[NPB * TST];

    const int tid  = threadIdx.x;
    const int lane = tid & 63;
    const int w    = tid >> 6;
    const int lr   = lane & 15;
    const int lk   = (lane >> 4) * 8;
    const int c0   = w * 32;
    const int n0   = blockIdx.x * NPB;

    #pragma unroll
    for (int p = 0; p < 4; ++p) {
        const int slot  = p * 16 + (tid >> 4);
        const int pc    = tid & 15;
        const int s     = slot & 31;
        const int isagg = slot >> 5;
        int n = n0 + s; if (n >= NN) n = NN - 1;
        short8v v;
        if (MODE == 2) {
            const unsigned short* src = isagg ? (agg_bf + (size_t)n * HD)
                                              : (hb + (size_t)n * HD);
            v = *reinterpret_cast<const short8v*>(src + pc * 8);
        } else {
            const float* src = isagg ? (agg_f32 + (size_t)n * HD)
                                     : (h + (size_t)n * HD);
            float4 f0 = *reinterpret_cast<const float4*>(src + pc * 8);
            float4 f1 = *reinterpret_cast<const float4*>(src + pc * 8 + 4);
            v[0] = (short)f2bf(f0.x); v[1] = (short)f2bf(f0.y);
            v[2] = (short)f2bf(f0.z); v[3] = (short)f2bf(f0.w);
            v[4] = (short)f2bf(f1.x); v[5] = (short)f2bf(f1.y);
            v[6] = (short)f2bf(f1.z); v[7] = (short)f2bf(f1.w);
        }
        *reinterpret_cast<short8v*>(&Xn[s * NXST + isagg * 128 + pc * 8]) = v;
    }
    __syncthreads();

    f32x4 acc1[2][2] = {};
    {
        const unsigned short* xa0 = &Xn[lr * NXST + lk];
        const unsigned short* xa1 = xa0 + 16 * NXST;
        const unsigned short* wb0 = n1t + (size_t)(c0 + lr) * 256 + lk;
        const unsigned short* wb1 = wb0 + 16 * 256;
        __builtin_amdgcn_s_setprio(1);
        #pragma unroll
        for (int ks = 0; ks < 8; ++ks) {
            const int k0 = ks * 32;
            short8v a0 = *reinterpret_cast<const short8v*>(xa0 + k0);
            short8v a1 = *reinterpret_cast<const short8v*>(xa1 + k0);
            short8v b0 = *reinterpret_cast<const short8v*>(wb0 + k0);
            short8v b1 = *reinterpret_cast<const short8v*>(wb1 + k0);
            acc1[0][0] = MFMA_BF16(a0, b0, acc1[0][0]);
            acc1[0][1] = MFMA_BF16(a0, b1, acc1[0][1]);
            acc1[1][0] = MFMA_BF16(a1, b0, acc1[1][0]);
            acc1[1][1] = MFMA_BF16(a1, b1, acc1[1][1]);
        }
        __builtin_amdgcn_s_setprio(0);
    }
    {
        const float b1a = nb1[c0 + lr];
        const float b1b = nb1[c0 + 16 + lr];
        #pragma unroll
        for (int mt = 0; mt < 2; ++mt)
            #pragma unroll
            for (int nt = 0; nt < 2; ++nt) {
                const int n = c0 + nt * 16 + lr;
                const float bb = nt ? b1b : b1a;
                #pragma unroll
                for (int r = 0; r < 4; ++r) {
                    const int m = mt * 16 + (lane >> 4) * 4 + r;
                    Tn[m * TST + n] = f2bf(silu(acc1[mt][nt][r] + bb));
                }
            }
    }
    __syncthreads();

    f32x4 acc2[2][2] = {};
    {
        const unsigned short* ta0 = &Tn[lr * TST + lk];
        const unsigned short* ta1 = ta0 + 16 * TST;
        const unsigned short* wb0 = n2t + (size_t)(c0 + lr) * 128 + lk;
        const unsigned short* wb1 = wb0 + 16 * 128;
        __builtin_amdgcn_s_setprio(1);
        #pragma unroll
        for (int ks = 0; ks < 4; ++ks) {
            const int k0 = ks * 32;
            short8v a0 = *reinterpret_cast<const short8v*>(ta0 + k0);
            short8v a1 = *reinterpret_cast<const short8v*>(ta1 + k0);
            short8v b0 = *reinterpret_cast<const short8v*>(wb0 + k0);
            short8v b1 = *reinterpret_cast<const short8v*>(wb1 + k0);
            acc2[0][0] = MFMA_BF16(a0, b0, acc2[0][0]);
            acc2[0][1] = MFMA_BF16(a0, b1, acc2[0][1]);
            acc2[1][0] = MFMA_BF16(a1, b0, acc2[1][0]);
            acc2[1][1] = MFMA_BF16(a1, b1, acc2[1][1]);
        }
        __builtin_amdgcn_s_setprio(0);
    }
    {
        const float b2a = nb2[c0 + lr];
        const float b2b = nb2[c0 + 16 + lr];
        #pragma unroll
        for (int mt = 0; mt < 2; ++mt)
            #pragma unroll
            for (int nt = 0; nt < 2; ++nt) {
                const int n = c0 + nt * 16 + lr;
                const float bb = nt ? b2b : b2a;
                #pragma unroll
                for (int r = 0; r < 4; ++r) {
                    const int m = mt * 16 + (lane >> 4) * 4 + r;
                    const int node = n0 + m;
                    if (node < NN) {
                        const size_t o = (size_t)node * HD + n;
                        out_h[o] = h[o] + acc2[mt][nt][r] + bb;
                    }
                }
            }
    }
    if (tid < NPB * 3) {
        const int s = tid / 3, a = tid % 3;
        const int node = n0 + s;
        if (node < NN) {
            const size_t idx = (size_t)node * 3 + a;
            out_pos[idx] = pos[idx] + out_pos[idx];
        }
    }
}

extern "C" void kernel_launch(void* const* d_in, const int* in_sizes, int n_in,
                              void* d_out, int out_size, void* d_ws, size_t ws_size,
                              hipStream_t stream) {
    const float* h   = (const float*)d_in[0];
    const float* pos = (const float*)d_in[1];
    const int*   ei  = (const int*)d_in[2];
    const float* mw1 = (const float*)d_in[3];
    const float* mb1 = (const float*)d_in[4];
    const float* mw2 = (const float*)d_in[5];
    const float* mb2 = (const float*)d_in[6];
    const float* cw1 = (const float*)d_in[7];
    const float* cb1 = (const float*)d_in[8];
    const float* cw2 = (const float*)d_in[9];
    const float* cb2 = (const float*)d_in[10];
    const float* nw1 = (const float*)d_in[11];
    const float* nb1 = (const float*)d_in[12];
    const float* nw2 = (const float*)d_in[13];
    const float* nb2 = (const float*)d_in[14];

    float* out     = (float*)d_out;
    float* out_h   = out;
    float* out_pos = out + (size_t)NN * HD;

    // ws layout (bf16): [wt: WTOT][hb: NN*HD][agg_bf: NN*HD]
    unsigned short* wt   = (unsigned short*)d_ws;
    unsigned short* w1t  = wt;
    unsigned short* w2t  = wt + W1T_N;
    unsigned short* n1t  = wt + W1T_N + W2T_N;
    unsigned short* n2t  = wt + W1T_N + W2T_N + N1T_N;
    unsigned short* cw1p = wt + W1T_N + W2T_N + N1T_N + N2T_N;
    unsigned short* hb   = wt + WTOT;
    unsigned short* agg_bf = hb + (size_t)NN * HD;
    const size_t need = (size_t)WTOT * 2 + 2 * (size_t)NN * HD * 2;
    const int mode2 = (ws_size >= need) ? 1 : 0;

    prep_weights<<<(WTOT + 255) / 256, 256, 0, stream>>>(mw1, mw2, nw1, nw2, cw1, wt);

    if (mode2) {
        prep_h<<<(NN * HD / 4 + 255) / 256, 256, 0, stream>>>(h, hb);
        hipMemsetAsync(agg_bf, 0, (size_t)NN * HD * 2, stream);
        hipMemsetAsync(out_pos, 0, (size_t)NN * 3 * sizeof(float), stream);
        egnn_edge_wa<2><<<NB_E, 256, 0, stream>>>(
            h, hb, pos, ei, w1t, mb1, w2t, mb2, cw1p, cb1, cw2, cb2,
            out_h, agg_bf, out_pos);
        egnn_node_mfma<2><<<NB_N, 256, 0, stream>>>(
            h, hb, pos, n1t, nb1, n2t, nb2, out_h, agg_bf, out_h, out_pos);
    } else {
        hipMemsetAsync(d_out, 0, (size_t)out_size * sizeof(float), stream);
        egnn_edge_wa<0><<<NB_E, 256, 0, stream>>>(
            h, hb, pos, ei, w1t, mb1, w2t, mb2, cw1p, cb1, cw2, cb2,
            out_h, agg_bf, out_pos);
        egnn_node_mfma<0><<<NB_N, 256, 0, stream>>>(
            h, hb, pos, n1t, nb1, n2t, nb2, out_h, agg_bf, out_h, out_pos);
    }
}

// Round 11
// 279.274 us; speedup vs baseline: 1.4877x; 1.4877x over previous
//
#include <hip/hip_runtime.h>

#define HD 128
#define NN 50000
#define NE 600000
#define EPB 64            // edges per block (edge kernel)
#define NPB 32            // nodes per block (node kernel)
#define XST 296           // edge X LDS row stride (bf16)
#define TST 136           // T/M LDS row stride (bf16)
#define K1P 288           // padded K for edge layer1
#define NXST 264          // node X LDS row stride (bf16)
#define NB_E (NE / EPB)   // 9375
#define NB_N ((NN + NPB - 1) / NPB)

typedef __attribute__((ext_vector_type(8))) short short8v;
typedef __attribute__((ext_vector_type(4))) short short4v;
typedef __attribute__((ext_vector_type(4))) float f32x4;

#define MFMA_BF16(a, b, c) __builtin_amdgcn_mfma_f32_16x16x32_bf16(a, b, c, 0, 0, 0)

__device__ __forceinline__ float silu(float x) {
    return x / (1.0f + __expf(-x));
}
__device__ __forceinline__ unsigned short f2bf(float x) {   // RNE f32 -> bf16
    unsigned u = __float_as_uint(x);
    unsigned r = (u + 0x7FFFu + ((u >> 16) & 1u)) >> 16;
    return (unsigned short)r;
}
__device__ __forceinline__ float bf2f(unsigned short u) {
    return __uint_as_float((unsigned)u << 16);
}
__device__ __forceinline__ void atomic_pk_bf16(unsigned short* dst, unsigned pk) {
    asm volatile("global_atomic_pk_add_bf16 %0, %1, off" :: "v"(dst), "v"(pk) : "memory");
}

// ---- prep: transpose+convert weights to bf16 in ws ----
// layout: w1t[128][288] | w2t[128][128] | n1t[128][256] | n2t[128][128] | cw1p[16][128]
#define W1T_N (128 * K1P)
#define W2T_N (128 * 128)
#define N1T_N (128 * 256)
#define N2T_N (128 * 128)
#define C1P_N (16 * 128)
#define WTOT  (W1T_N + W2T_N + N1T_N + N2T_N + C1P_N)  // 104448

__global__ __launch_bounds__(256) void prep_weights(
    const float* __restrict__ mw1, const float* __restrict__ mw2,
    const float* __restrict__ nw1, const float* __restrict__ nw2,
    const float* __restrict__ cw1, unsigned short* __restrict__ wt)
{
    int idx = blockIdx.x * 256 + threadIdx.x;
    if (idx < W1T_N) {
        int c = idx / K1P, k = idx % K1P;
        wt[idx] = (k < 257) ? f2bf(mw1[(size_t)k * HD + c]) : (unsigned short)0;
    } else if (idx < W1T_N + W2T_N) {
        int i = idx - W1T_N;
        int c = i / 128, k = i % 128;
        wt[idx] = f2bf(mw2[(size_t)k * HD + c]);
    } else if (idx < W1T_N + W2T_N + N1T_N) {
        int i = idx - (W1T_N + W2T_N);
        int c = i / 256, k = i % 256;
        wt[idx] = f2bf(nw1[(size_t)k * HD + c]);
    } else if (idx < W1T_N + W2T_N + N1T_N + N2T_N) {
        int i = idx - (W1T_N + W2T_N + N1T_N);
        int c = i / 128, k = i % 128;
        wt[idx] = f2bf(nw2[(size_t)k * HD + c]);
    } else if (idx < WTOT) {
        int i = idx - (W1T_N + W2T_N + N1T_N + N2T_N);
        int n = i / 128, k = i % 128;
        wt[idx] = (n < 4) ? f2bf(cw1[(size_t)k * 4 + n]) : (unsigned short)0;
    }
}

__global__ __launch_bounds__(256) void prep_h(
    const float* __restrict__ h, unsigned short* __restrict__ hb)
{
    size_t idx = (size_t)(blockIdx.x * 256 + threadIdx.x) * 4;
    float4 f = *reinterpret_cast<const float4*>(h + idx);
    short4v v;
    v[0] = (short)f2bf(f.x); v[1] = (short)f2bf(f.y);
    v[2] = (short)f2bf(f.z); v[3] = (short)f2bf(f.w);
    *reinterpret_cast<short4v*>(hb + idx) = v;
}

// ============ edge kernel: 64 edges/block, 4 waves x (64x32 tile) ============
// MODE 0: f32 gather, f32 atomics into agg_f32. MODE 2: bf16 gather, pk-bf16 atomics.
// Tail order (MODE2): B4 -> coord-MLP (LDS + reg weights only) -> trans atomics
// -> msg pk-scatter LAST. No vmem-consuming instruction after the first atomic
// => atomics are genuinely fire-and-forget (no in-order vmcnt drain).
template <int MODE>
__global__ __launch_bounds__(256, 4) void egnn_edge_mfma(
    const float* __restrict__ h, const unsigned short* __restrict__ hb,
    const float* __restrict__ pos, const int* __restrict__ ei,
    const unsigned short* __restrict__ w1t, const float* __restrict__ mb1,
    const unsigned short* __restrict__ w2t, const float* __restrict__ mb2,
    const unsigned short* __restrict__ cw1p, const float* __restrict__ cb1,
    const float* __restrict__ cw2, const float* __restrict__ cb2,
    float* __restrict__ agg_f32, unsigned short* __restrict__ agg_bf,
    float* __restrict__ agg_trans)
{
    // X live ranges: A) gathered [h_r|h_c|radial|pad] (18944 entries);
    //                B) T (silu L1) in [0, 8704);  C) M (msg bf16) in [8704, 17408)
    __shared__ __align__(16) unsigned short X[EPB * XST];
    __shared__ int rows[EPB];
    __shared__ float cd[EPB][3];

    const int tid  = threadIdx.x;
    const int lane = tid & 63;
    const int w    = tid >> 6;
    const int lr   = lane & 15;
    const int lk   = (lane >> 4) * 8;
    const int c0   = w * 32;
    const int e0   = blockIdx.x * EPB;

    // ---- phase 0 ----
    if (tid < EPB) {
        const int r = ei[e0 + tid];
        const int c = ei[(size_t)NE + e0 + tid];
        rows[tid] = r;
        const float d0 = pos[r * 3 + 0] - pos[c * 3 + 0];
        const float d1 = pos[r * 3 + 1] - pos[c * 3 + 1];
        const float d2 = pos[r * 3 + 2] - pos[c * 3 + 2];
        cd[tid][0] = d0; cd[tid][1] = d1; cd[tid][2] = d2;
        X[tid * XST + 256] = f2bf(d0 * d0 + d1 * d1 + d2 * d2 + 1e-8f);
    }
    for (int idx = tid; idx < EPB * 31; idx += 256) {   // zero pad cols 257..287
        const int e = idx / 31, c = 257 + idx % 31;
        X[e * XST + c] = 0;
    }
    #pragma unroll
    for (int p = 0; p < 8; ++p) {       // 128 row-slots x 256B, 16 thr x 16B each
        const int slot  = p * 16 + (tid >> 4);
        const int pc    = tid & 15;
        const int e     = slot & 63;
        const int iscol = slot >> 6;
        const int src   = ei[(size_t)(iscol ? NE : 0) + e0 + e];
        short8v v;
        if (MODE >= 1) {
            v = *reinterpret_cast<const short8v*>(hb + (size_t)src * HD + pc * 8);
        } else {
            const float* hp = h + (size_t)src * HD + pc * 8;
            float4 f0 = *reinterpret_cast<const float4*>(hp);
            float4 f1 = *reinterpret_cast<const float4*>(hp + 4);
            v[0] = (short)f2bf(f0.x); v[1] = (short)f2bf(f0.y);
            v[2] = (short)f2bf(f0.z); v[3] = (short)f2bf(f0.w);
            v[4] = (short)f2bf(f1.x); v[5] = (short)f2bf(f1.y);
            v[6] = (short)f2bf(f1.z); v[7] = (short)f2bf(f1.w);
        }
        *reinterpret_cast<short8v*>(&X[e * XST + iscol * 128 + pc * 8]) = v;
    }
    __syncthreads();   // B1: X complete

    // ---- preload coord-MLP weight fragments (completes under layer-1 MFMAs;
    //      MUST be issued before any atomic so the tail has no vmem loads) ----
    short8v cwf[4];
    #pragma unroll
    for (int ks = 0; ks < 4; ++ks)
        cwf[ks] = *reinterpret_cast<const short8v*>(cw1p + (size_t)lr * 128 + lk + ks * 32);

    // ---- layer 1: X[64,288] @ W1T^T (64x32 tile per wave) ----
    f32x4 acc1[4][2] = {};
    {
        const unsigned short* xa = &X[lr * XST + lk];
        const unsigned short* wb0 = w1t + (size_t)(c0 + lr) * K1P + lk;
        const unsigned short* wb1 = wb0 + 16 * K1P;
        __builtin_amdgcn_s_setprio(1);
        #pragma unroll
        for (int ks = 0; ks < 9; ++ks) {
            const int k0 = ks * 32;
            short8v b0 = *reinterpret_cast<const short8v*>(wb0 + k0);
            short8v b1 = *reinterpret_cast<const short8v*>(wb1 + k0);
            #pragma unroll
            for (int mt = 0; mt < 4; ++mt) {
                short8v a = *reinterpret_cast<const short8v*>(xa + mt * 16 * XST + k0);
                acc1[mt][0] = MFMA_BF16(a, b0, acc1[mt][0]);
                acc1[mt][1] = MFMA_BF16(a, b1, acc1[mt][1]);
            }
        }
        __builtin_amdgcn_s_setprio(0);
    }
    __syncthreads();   // B2: X reads retired -> safe to alias

    {   // silu -> T (aliased into X[0, 8704))
        unsigned short* T = X;
        const float b1a = mb1[c0 + lr];
        const float b1b = mb1[c0 + 16 + lr];
        #pragma unroll
        for (int mt = 0; mt < 4; ++mt)
            #pragma unroll
            for (int nt = 0; nt < 2; ++nt) {
                const int n = c0 + nt * 16 + lr;
                const float bb = nt ? b1b : b1a;
                #pragma unroll
                for (int r = 0; r < 4; ++r) {
                    const int m = mt * 16 + (lane >> 4) * 4 + r;
                    T[m * TST + n] = f2bf(silu(acc1[mt][nt][r] + bb));
                }
            }
    }
    __syncthreads();   // B3: T complete

    // ---- layer 2: T[64,128] @ W2T^T -> msg ----
    f32x4 acc2[4][2] = {};
    {
        const unsigned short* ta = &X[lr * TST + lk];
        const unsigned short* wb0 = w2t + (size_t)(c0 + lr) * 128 + lk;
        const unsigned short* wb1 = wb0 + 16 * 128;
        __builtin_amdgcn_s_setprio(1);
        #pragma unroll
        for (int ks = 0; ks < 4; ++ks) {
            const int k0 = ks * 32;
            short8v b0 = *reinterpret_cast<const short8v*>(wb0 + k0);
            short8v b1 = *reinterpret_cast<const short8v*>(wb1 + k0);
            #pragma unroll
            for (int mt = 0; mt < 4; ++mt) {
                short8v a = *reinterpret_cast<const short8v*>(ta + mt * 16 * TST + k0);
                acc2[mt][0] = MFMA_BF16(a, b0, acc2[mt][0]);
                acc2[mt][1] = MFMA_BF16(a, b1, acc2[mt][1]);
            }
        }
        __builtin_amdgcn_s_setprio(0);
    }
    {   // msg -> M (bf16, X entries [8704, 17408)); MODE0 also f32 atomics
        unsigned short* M = X + 8704;
        const float b2a = mb2[c0 + lr];
        const float b2b = mb2[c0 + 16 + lr];
        #pragma unroll
        for (int mt = 0; mt < 4; ++mt)
            #pragma unroll
            for (int nt = 0; nt < 2; ++nt) {
                const int n = c0 + nt * 16 + lr;
                const float bb = nt ? b2b : b2a;
                #pragma unroll
                for (int r = 0; r < 4; ++r) {
                    const int m = mt * 16 + (lane >> 4) * 4 + r;
                    const float v = acc2[mt][nt][r] + bb;
                    M[m * TST + n] = f2bf(v);
                    if (MODE == 0)
                        atomicAdd(&agg_f32[(size_t)rows[m] * HD + n], v);
                }
            }
    }
    __syncthreads();   // B4: M complete — LAST barrier

    // ---- coord MLP via MFMA FIRST (LDS + registers only; no vmem loads) ----
    {
        const unsigned short* M = X + 8704;
        f32x4 accc = {};
        const unsigned short* ma = &M[(w * 16 + lr) * TST + lk];
        #pragma unroll
        for (int ks = 0; ks < 4; ++ks) {
            short8v a = *reinterpret_cast<const short8v*>(ma + ks * 32);
            accc = MFMA_BF16(a, cwf[ks], accc);
        }
        const int q = lr;                       // output col (0..15, valid 0..3)
        const float b1q = (q < 4) ? cb1[q] : 0.f;
        const float c2q = (q < 4) ? cw2[q] : 0.f;
        const float cb2v = cb2[0];
        #pragma unroll
        for (int r = 0; r < 4; ++r) {
            float t = silu(accc[r] + b1q) * c2q;
            t += __shfl_xor(t, 1);
            t += __shfl_xor(t, 2);              // lanes q=0..3 hold sum over q
            const float cwt = t + cb2v;
            if (q < 3) {
                const int e = w * 16 + (lane >> 4) * 4 + r;
                atomicAdd(&agg_trans[rows[e] * 3 + q], cd[e][q] * cwt);
            }
        }
    }

    // ---- MODE2: msg pk-scatter DEAD LAST (nothing vmem-dependent after) ----
    if (MODE == 2) {
        const unsigned short* M = X + 8704;
        #pragma unroll
        for (int t = 0; t < 16; ++t) {
            const int idx = t * 256 + tid;     // 0..4095
            const int e   = idx >> 6;          // edge slot (wave-uniform)
            const int pc  = idx & 63;          // channel pair
            const unsigned pk = *reinterpret_cast<const unsigned*>(&M[e * TST + pc * 2]);
            atomic_pk_bf16(agg_bf + ((size_t)rows[e] * HD + pc * 2), pk);
        }
    }
}

// ============ node kernel ============
template <int MODE>
__global__ __launch_bounds__(256, 6) void egnn_node_mfma(
    const float* __restrict__ h, const unsigned short* __restrict__ hb,
    const float* __restrict__ pos,
    const unsigned short* __restrict__ n1t, const float* __restrict__ nb1,
    const unsigned short* __restrict__ n2t, const float* __restrict__ nb2,
    const float* __restrict__ agg_f32, const unsigned short* __restrict__ agg_bf,
    float* __restrict__ out_h, float* __restrict__ out_pos)
{
    __shared__ __align__(16) unsigned short Xn[NPB * NXST];
    __shared__ __align__(16) unsigned short Tn[NPB * TST];

    const int tid  = threadIdx.x;
    const int lane = tid & 63;
    const int w    = tid >> 6;
    const int lr   = lane & 15;
    const int lk   = (lane >> 4) * 8;
    const int c0   = w * 32;
    const int n0   = blockIdx.x * NPB;

    #pragma unroll
    for (int p = 0; p < 4; ++p) {
        const int slot  = p * 16 + (tid >> 4);
        const int pc    = tid & 15;
        const int s     = slot & 31;
        const int isagg = slot >> 5;
        int n = n0 + s; if (n >= NN) n = NN - 1;
        short8v v;
        if (MODE == 2) {
            const unsigned short* src = isagg ? (agg_bf + (size_t)n * HD)
                                              : (hb + (size_t)n * HD);
            v = *reinterpret_cast<const short8v*>(src + pc * 8);
        } else {
            const float* src = isagg ? (agg_f32 + (size_t)n * HD)
                                     : (h + (size_t)n * HD);
            float4 f0 = *reinterpret_cast<const float4*>(src + pc * 8);
            float4 f1 = *reinterpret_cast<const float4*>(src + pc * 8 + 4);
            v[0] = (short)f2bf(f0.x); v[1] = (short)f2bf(f0.y);
            v[2] = (short)f2bf(f0.z); v[3] = (short)f2bf(f0.w);
            v[4] = (short)f2bf(f1.x); v[5] = (short)f2bf(f1.y);
            v[6] = (short)f2bf(f1.z); v[7] = (short)f2bf(f1.w);
        }
        *reinterpret_cast<short8v*>(&Xn[s * NXST + isagg * 128 + pc * 8]) = v;
    }
    __syncthreads();

    f32x4 acc1[2][2] = {};
    {
        const unsigned short* xa0 = &Xn[lr * NXST + lk];
        const unsigned short* xa1 = xa0 + 16 * NXST;
        const unsigned short* wb0 = n1t + (size_t)(c0 + lr) * 256 + lk;
        const unsigned short* wb1 = wb0 + 16 * 256;
        __builtin_amdgcn_s_setprio(1);
        #pragma unroll
        for (int ks = 0; ks < 8; ++ks) {
            const int k0 = ks * 32;
            short8v a0 = *reinterpret_cast<const short8v*>(xa0 + k0);
            short8v a1 = *reinterpret_cast<const short8v*>(xa1 + k0);
            short8v b0 = *reinterpret_cast<const short8v*>(wb0 + k0);
            short8v b1 = *reinterpret_cast<const short8v*>(wb1 + k0);
            acc1[0][0] = MFMA_BF16(a0, b0, acc1[0][0]);
            acc1[0][1] = MFMA_BF16(a0, b1, acc1[0][1]);
            acc1[1][0] = MFMA_BF16(a1, b0, acc1[1][0]);
            acc1[1][1] = MFMA_BF16(a1, b1, acc1[1][1]);
        }
        __builtin_amdgcn_s_setprio(0);
    }
    {
        const float b1a = nb1[c0 + lr];
        const float b1b = nb1[c0 + 16 + lr];
        #pragma unroll
        for (int mt = 0; mt < 2; ++mt)
            #pragma unroll
            for (int nt = 0; nt < 2; ++nt) {
                const int n = c0 + nt * 16 + lr;
                const float bb = nt ? b1b : b1a;
                #pragma unroll
                for (int r = 0; r < 4; ++r) {
                    const int m = mt * 16 + (lane >> 4) * 4 + r;
                    Tn[m * TST + n] = f2bf(silu(acc1[mt][nt][r] + bb));
                }
            }
    }
    __syncthreads();

    f32x4 acc2[2][2] = {};
    {
        const unsigned short* ta0 = &Tn[lr * TST + lk];
        const unsigned short* ta1 = ta0 + 16 * TST;
        const unsigned short* wb0 = n2t + (size_t)(c0 + lr) * 128 + lk;
        const unsigned short* wb1 = wb0 + 16 * 128;
        __builtin_amdgcn_s_setprio(1);
        #pragma unroll
        for (int ks = 0; ks < 4; ++ks) {
            const int k0 = ks * 32;
            short8v a0 = *reinterpret_cast<const short8v*>(ta0 + k0);
            short8v a1 = *reinterpret_cast<const short8v*>(ta1 + k0);
            short8v b0 = *reinterpret_cast<const short8v*>(wb0 + k0);
            short8v b1 = *reinterpret_cast<const short8v*>(wb1 + k0);
            acc2[0][0] = MFMA_BF16(a0, b0, acc2[0][0]);
            acc2[0][1] = MFMA_BF16(a0, b1, acc2[0][1]);
            acc2[1][0] = MFMA_BF16(a1, b0, acc2[1][0]);
            acc2[1][1] = MFMA_BF16(a1, b1, acc2[1][1]);
        }
        __builtin_amdgcn_s_setprio(0);
    }
    {
        const float b2a = nb2[c0 + lr];
        const float b2b = nb2[c0 + 16 + lr];
        #pragma unroll
        for (int mt = 0; mt < 2; ++mt)
            #pragma unroll
            for (int nt = 0; nt < 2; ++nt) {
                const int n = c0 + nt * 16 + lr;
                const float bb = nt ? b2b : b2a;
                #pragma unroll
                for (int r = 0; r < 4; ++r) {
                    const int m = mt * 16 + (lane >> 4) * 4 + r;
                    const int node = n0 + m;
                    if (node < NN) {
                        const size_t o = (size_t)node * HD + n;
                        out_h[o] = h[o] + acc2[mt][nt][r] + bb;
                    }
                }
            }
    }
    if (tid < NPB * 3) {
        const int s = tid / 3, a = tid % 3;
        const int node = n0 + s;
        if (node < NN) {
            const size_t idx = (size_t)node * 3 + a;
            out_pos[idx] = pos[idx] + out_pos[idx];
        }
    }
}

extern "C" void kernel_launch(void* const* d_in, const int* in_sizes, int n_in,
                              void* d_out, int out_size, void* d_ws, size_t ws_size,
                              hipStream_t stream) {
    const float* h   = (const float*)d_in[0];
    const float* pos = (const float*)d_in[1];
    const int*   ei  = (const int*)d_in[2];
    const float* mw1 = (const float*)d_in[3];
    const float* mb1 = (const float*)d_in[4];
    const float* mw2 = (const float*)d_in[5];
    const float* mb2 = (const float*)d_in[6];
    const float* cw1 = (const float*)d_in[7];
    const float* cb1 = (const float*)d_in[8];
    const float* cw2 = (const float*)d_in[9];
    const float* cb2 = (const float*)d_in[10];
    const float* nw1 = (const float*)d_in[11];
    const float* nb1 = (const float*)d_in[12];
    const float* nw2 = (const float*)d_in[13];
    const float* nb2 = (const float*)d_in[14];

    float* out     = (float*)d_out;
    float* out_h   = out;
    float* out_pos = out + (size_t)NN * HD;

    // ws layout (bf16): [wt: WTOT][hb: NN*HD][agg_bf: NN*HD]
    unsigned short* wt   = (unsigned short*)d_ws;
    unsigned short* w1t  = wt;
    unsigned short* w2t  = wt + W1T_N;
    unsigned short* n1t  = wt + W1T_N + W2T_N;
    unsigned short* n2t  = wt + W1T_N + W2T_N + N1T_N;
    unsigned short* cw1p = wt + W1T_N + W2T_N + N1T_N + N2T_N;
    unsigned short* hb   = wt + WTOT;
    unsigned short* agg_bf = hb + (size_t)NN * HD;
    const size_t need = (size_t)WTOT * 2 + 2 * (size_t)NN * HD * 2;
    const int mode2 = (ws_size >= need) ? 1 : 0;

    prep_weights<<<(WTOT + 255) / 256, 256, 0, stream>>>(mw1, mw2, nw1, nw2, cw1, wt);

    if (mode2) {
        prep_h<<<(NN * HD / 4 + 255) / 256, 256, 0, stream>>>(h, hb);
        hipMemsetAsync(agg_bf, 0, (size_t)NN * HD * 2, stream);
        hipMemsetAsync(out_pos, 0, (size_t)NN * 3 * sizeof(float), stream);
        egnn_edge_mfma<2><<<NB_E, 256, 0, stream>>>(
            h, hb, pos, ei, w1t, mb1, w2t, mb2, cw1p, cb1, cw2, cb2,
            out_h, agg_bf, out_pos);
        egnn_node_mfma<2><<<NB_N, 256, 0, stream>>>(
            h, hb, pos, n1t, nb1, n2t, nb2, out_h, agg_bf, out_h, out_pos);
    } else {
        hipMemsetAsync(d_out, 0, (size_t)out_size * sizeof(float), stream);
        egnn_edge_mfma<0><<<NB_E, 256, 0, stream>>>(
            h, hb, pos, ei, w1t, mb1, w2t, mb2, cw1p, cb1, cw2, cb2,
            out_h, agg_bf, out_pos);
        egnn_node_mfma<0><<<NB_N, 256, 0, stream>>>(
            h, hb, pos, n1t, nb1, n2t, nb2, out_h, agg_bf, out_h, out_pos);
    }
}

// Round 12
// 272.164 us; speedup vs baseline: 1.5266x; 1.0261x over previous
//
#include <hip/hip_runtime.h>

#define HD 128
#define NN 50000
#define NE 600000
#define EPB 64            // edges per block (edge kernel)
#define NPB 32            // nodes per block (node kernel)
#define XST 296           // edge X LDS row stride (bf16)
#define TST 136           // T/M LDS row stride (bf16)
#define K1P 288           // padded K for edge layer1
#define NXST 264          // node X LDS row stride (bf16)
#define NB_E (NE / EPB)   // 9375
#define NB_N ((NN + NPB - 1) / NPB)

typedef __attribute__((ext_vector_type(8))) short short8v;
typedef __attribute__((ext_vector_type(4))) short short4v;
typedef __attribute__((ext_vector_type(4))) float f32x4;

#define MFMA_BF16(a, b, c) __builtin_amdgcn_mfma_f32_16x16x32_bf16(a, b, c, 0, 0, 0)

// fast silu: rcp instead of full-precision divide (error ~2^-21, invisible in bf16)
__device__ __forceinline__ float silu(float x) {
    const float e = __expf(-x);
    return x * __builtin_amdgcn_rcpf(1.0f + e);
}
__device__ __forceinline__ unsigned short f2bf(float x) {   // RNE f32 -> bf16 (prep only)
    unsigned u = __float_as_uint(x);
    unsigned r = (u + 0x7FFFu + ((u >> 16) & 1u)) >> 16;
    return (unsigned short)r;
}
__device__ __forceinline__ float bf2f(unsigned short u) {
    return __uint_as_float((unsigned)u << 16);
}
// pack two f32 -> two bf16 (RNE) in one instruction
__device__ __forceinline__ unsigned cvt_pk_bf16(float lo, float hi) {
    unsigned r;
    asm("v_cvt_pk_bf16_f32 %0, %1, %2" : "=v"(r) : "v"(lo), "v"(hi));
    return r;
}
__device__ __forceinline__ void atomic_pk_bf16(unsigned short* dst, unsigned pk) {
    asm volatile("global_atomic_pk_add_bf16 %0, %1, off" :: "v"(dst), "v"(pk) : "memory");
}

// ---- prep: transpose+convert weights to bf16 in ws ----
// layout: w1t[128][288] | w2t[128][128] | n1t[128][256] | n2t[128][128] | cw1p[16][128]
// Row PERMUTATION (w1t/w2t/n1t/n2t): storage row s holds output channel
// c = (s & ~31) + 2*(s & 15) + ((s>>4) & 1), so each MFMA thread's two
// output-tile channels are ADJACENT (enables cvt_pk paired bf16 stores).
#define W1T_N (128 * K1P)
#define W2T_N (128 * 128)
#define N1T_N (128 * 256)
#define N2T_N (128 * 128)
#define C1P_N (16 * 128)
#define WTOT  (W1T_N + W2T_N + N1T_N + N2T_N + C1P_N)  // 104448

__device__ __forceinline__ int perm_ch(int s) {
    return (s & ~31) | (2 * (s & 15) + ((s >> 4) & 1));
}

__global__ __launch_bounds__(256) void prep_weights(
    const float* __restrict__ mw1, const float* __restrict__ mw2,
    const float* __restrict__ nw1, const float* __restrict__ nw2,
    const float* __restrict__ cw1, unsigned short* __restrict__ wt)
{
    int idx = blockIdx.x * 256 + threadIdx.x;
    if (idx < W1T_N) {
        int s = idx / K1P, k = idx % K1P;
        int c = perm_ch(s);
        wt[idx] = (k < 257) ? f2bf(mw1[(size_t)k * HD + c]) : (unsigned short)0;
    } else if (idx < W1T_N + W2T_N) {
        int i = idx - W1T_N;
        int s = i / 128, k = i % 128;
        wt[idx] = f2bf(mw2[(size_t)k * HD + perm_ch(s)]);
    } else if (idx < W1T_N + W2T_N + N1T_N) {
        int i = idx - (W1T_N + W2T_N);
        int s = i / 256, k = i % 256;
        wt[idx] = f2bf(nw1[(size_t)k * HD + perm_ch(s)]);
    } else if (idx < W1T_N + W2T_N + N1T_N + N2T_N) {
        int i = idx - (W1T_N + W2T_N + N1T_N);
        int s = i / 128, k = i % 128;
        wt[idx] = f2bf(nw2[(size_t)k * HD + perm_ch(s)]);
    } else if (idx < WTOT) {
        int i = idx - (W1T_N + W2T_N + N1T_N + N2T_N);
        int n = i / 128, k = i % 128;
        wt[idx] = (n < 4) ? f2bf(cw1[(size_t)k * 4 + n]) : (unsigned short)0;
    }
}

__global__ __launch_bounds__(256) void prep_h(
    const float* __restrict__ h, unsigned short* __restrict__ hb)
{
    size_t idx = (size_t)(blockIdx.x * 256 + threadIdx.x) * 4;
    float4 f = *reinterpret_cast<const float4*>(h + idx);
    short4v v;
    v[0] = (short)f2bf(f.x); v[1] = (short)f2bf(f.y);
    v[2] = (short)f2bf(f.z); v[3] = (short)f2bf(f.w);
    *reinterpret_cast<short4v*>(hb + idx) = v;
}

// ============ edge kernel: 64 edges/block, 4 waves x (64x32 tile) ============
// MODE 0: f32 gather, f32 atomics into agg_f32. MODE 2: bf16 gather, pk-bf16 atomics.
// Thread's two output channels are adjacent (nlo, nlo+1) thanks to the weight
// row permutation -> paired cvt_pk stores. Tail: B4 -> coord-MLP (no vmem loads)
// -> trans atomics -> msg pk-scatter LAST (fire-and-forget).
template <int MODE>
__global__ __launch_bounds__(256, 4) void egnn_edge_mfma(
    const float* __restrict__ h, const unsigned short* __restrict__ hb,
    const float* __restrict__ pos, const int* __restrict__ ei,
    const unsigned short* __restrict__ w1t, const float* __restrict__ mb1,
    const unsigned short* __restrict__ w2t, const float* __restrict__ mb2,
    const unsigned short* __restrict__ cw1p, const float* __restrict__ cb1,
    const float* __restrict__ cw2, const float* __restrict__ cb2,
    float* __restrict__ agg_f32, unsigned short* __restrict__ agg_bf,
    float* __restrict__ agg_trans)
{
    // X live ranges: A) gathered [h_r|h_c|radial|pad] (18944 entries);
    //                B) T (silu L1) in [0, 8704);  C) M (msg bf16) in [8704, 17408)
    __shared__ __align__(16) unsigned short X[EPB * XST];
    __shared__ int rows[EPB];
    __shared__ float cd[EPB][3];

    const int tid  = threadIdx.x;
    const int lane = tid & 63;
    const int w    = tid >> 6;
    const int lr   = lane & 15;
    const int lk   = (lane >> 4) * 8;
    const int c0   = w * 32;
    const int nlo  = c0 + 2 * lr;      // this thread's adjacent channel pair
    const int e0   = blockIdx.x * EPB;

    // ---- phase 0 ----
    if (tid < EPB) {
        const int r = ei[e0 + tid];
        const int c = ei[(size_t)NE + e0 + tid];
        rows[tid] = r;
        const float d0 = pos[r * 3 + 0] - pos[c * 3 + 0];
        const float d1 = pos[r * 3 + 1] - pos[c * 3 + 1];
        const float d2 = pos[r * 3 + 2] - pos[c * 3 + 2];
        cd[tid][0] = d0; cd[tid][1] = d1; cd[tid][2] = d2;
        X[tid * XST + 256] = f2bf(d0 * d0 + d1 * d1 + d2 * d2 + 1e-8f);
    }
    #pragma unroll
    for (int j = 0; j < 8; ++j) {       // zero pad cols 257..287 (pow2 indexing)
        const int idx = j * 256 + tid;  // 0..2047
        const int e = idx >> 5, c = 256 + (idx & 31);
        if (c != 256) X[e * XST + c] = 0;
    }
    #pragma unroll
    for (int p = 0; p < 8; ++p) {       // 128 row-slots x 256B, 16 thr x 16B each
        const int slot  = p * 16 + (tid >> 4);
        const int pc    = tid & 15;
        const int e     = slot & 63;
        const int iscol = slot >> 6;
        const int src   = ei[(size_t)(iscol ? NE : 0) + e0 + e];
        short8v v;
        if (MODE >= 1) {
            v = *reinterpret_cast<const short8v*>(hb + (size_t)src * HD + pc * 8);
        } else {
            const float* hp = h + (size_t)src * HD + pc * 8;
            float4 f0 = *reinterpret_cast<const float4*>(hp);
            float4 f1 = *reinterpret_cast<const float4*>(hp + 4);
            v[0] = (short)f2bf(f0.x); v[1] = (short)f2bf(f0.y);
            v[2] = (short)f2bf(f0.z); v[3] = (short)f2bf(f0.w);
            v[4] = (short)f2bf(f1.x); v[5] = (short)f2bf(f1.y);
            v[6] = (short)f2bf(f1.z); v[7] = (short)f2bf(f1.w);
        }
        *reinterpret_cast<short8v*>(&X[e * XST + iscol * 128 + pc * 8]) = v;
    }
    __syncthreads();   // B1: X complete

    // ---- preload coord-MLP weight fragments (complete under layer-1 MFMAs;
    //      issued before any atomic so the tail has no vmem loads) ----
    short8v cwf[4];
    #pragma unroll
    for (int ks = 0; ks < 4; ++ks)
        cwf[ks] = *reinterpret_cast<const short8v*>(cw1p + (size_t)lr * 128 + lk + ks * 32);

    // ---- layer 1: X[64,288] @ W1T^T (64x32 tile per wave) ----
    f32x4 acc1[4][2] = {};
    {
        const unsigned short* xa = &X[lr * XST + lk];
        const unsigned short* wb0 = w1t + (size_t)(c0 + lr) * K1P + lk;
        const unsigned short* wb1 = wb0 + 16 * K1P;
        __builtin_amdgcn_s_setprio(1);
        #pragma unroll
        for (int ks = 0; ks < 9; ++ks) {
            const int k0 = ks * 32;
            short8v b0 = *reinterpret_cast<const short8v*>(wb0 + k0);
            short8v b1 = *reinterpret_cast<const short8v*>(wb1 + k0);
            #pragma unroll
            for (int mt = 0; mt < 4; ++mt) {
                short8v a = *reinterpret_cast<const short8v*>(xa + mt * 16 * XST + k0);
                acc1[mt][0] = MFMA_BF16(a, b0, acc1[mt][0]);
                acc1[mt][1] = MFMA_BF16(a, b1, acc1[mt][1]);
            }
        }
        __builtin_amdgcn_s_setprio(0);
    }
    __syncthreads();   // B2: X reads retired -> safe to alias

    {   // silu -> T (aliased into X[0, 8704)); paired cvt_pk stores
        unsigned short* T = X;
        const float2 b1v = *reinterpret_cast<const float2*>(&mb1[nlo]);
        #pragma unroll
        for (int mt = 0; mt < 4; ++mt)
            #pragma unroll
            for (int r = 0; r < 4; ++r) {
                const int m = mt * 16 + (lane >> 4) * 4 + r;
                const unsigned pk = cvt_pk_bf16(silu(acc1[mt][0][r] + b1v.x),
                                                silu(acc1[mt][1][r] + b1v.y));
                *reinterpret_cast<unsigned*>(&T[m * TST + nlo]) = pk;
            }
    }
    __syncthreads();   // B3: T complete

    // ---- layer 2: T[64,128] @ W2T^T -> msg ----
    f32x4 acc2[4][2] = {};
    {
        const unsigned short* ta = &X[lr * TST + lk];
        const unsigned short* wb0 = w2t + (size_t)(c0 + lr) * 128 + lk;
        const unsigned short* wb1 = wb0 + 16 * 128;
        __builtin_amdgcn_s_setprio(1);
        #pragma unroll
        for (int ks = 0; ks < 4; ++ks) {
            const int k0 = ks * 32;
            short8v b0 = *reinterpret_cast<const short8v*>(wb0 + k0);
            short8v b1 = *reinterpret_cast<const short8v*>(wb1 + k0);
            #pragma unroll
            for (int mt = 0; mt < 4; ++mt) {
                short8v a = *reinterpret_cast<const short8v*>(ta + mt * 16 * TST + k0);
                acc2[mt][0] = MFMA_BF16(a, b0, acc2[mt][0]);
                acc2[mt][1] = MFMA_BF16(a, b1, acc2[mt][1]);
            }
        }
        __builtin_amdgcn_s_setprio(0);
    }
    {   // msg -> M (bf16, X entries [8704, 17408)); MODE0 also f32 atomics
        unsigned short* M = X + 8704;
        const float2 b2v = *reinterpret_cast<const float2*>(&mb2[nlo]);
        #pragma unroll
        for (int mt = 0; mt < 4; ++mt)
            #pragma unroll
            for (int r = 0; r < 4; ++r) {
                const int m = mt * 16 + (lane >> 4) * 4 + r;
                const float v0 = acc2[mt][0][r] + b2v.x;
                const float v1 = acc2[mt][1][r] + b2v.y;
                *reinterpret_cast<unsigned*>(&M[m * TST + nlo]) = cvt_pk_bf16(v0, v1);
                if (MODE == 0) {
                    atomicAdd(&agg_f32[(size_t)rows[m] * HD + nlo], v0);
                    atomicAdd(&agg_f32[(size_t)rows[m] * HD + nlo + 1], v1);
                }
            }
    }
    __syncthreads();   // B4: M complete — LAST barrier

    // ---- coord MLP via MFMA FIRST (LDS + registers only; no vmem loads) ----
    {
        const unsigned short* M = X + 8704;
        f32x4 accc = {};
        const unsigned short* ma = &M[(w * 16 + lr) * TST + lk];
        #pragma unroll
        for (int ks = 0; ks < 4; ++ks) {
            short8v a = *reinterpret_cast<const short8v*>(ma + ks * 32);
            accc = MFMA_BF16(a, cwf[ks], accc);
        }
        const int q = lr;                       // output col (0..15, valid 0..3)
        const float b1q = (q < 4) ? cb1[q] : 0.f;
        const float c2q = (q < 4) ? cw2[q] : 0.f;
        const float cb2v = cb2[0];
        #pragma unroll
        for (int r = 0; r < 4; ++r) {
            float t = silu(accc[r] + b1q) * c2q;
            t += __shfl_xor(t, 1);
            t += __shfl_xor(t, 2);              // lanes q=0..3 hold sum over q
            const float cwt = t + cb2v;
            if (q < 3) {
                const int e = w * 16 + (lane >> 4) * 4 + r;
                atomicAdd(&agg_trans[rows[e] * 3 + q], cd[e][q] * cwt);
            }
        }
    }

    // ---- MODE2: msg pk-scatter DEAD LAST (nothing vmem-dependent after) ----
    if (MODE == 2) {
        const unsigned short* M = X + 8704;
        #pragma unroll
        for (int t = 0; t < 16; ++t) {
            const int idx = t * 256 + tid;     // 0..4095
            const int e   = idx >> 6;          // edge slot (wave-uniform)
            const int pc  = idx & 63;          // channel pair
            const unsigned pk = *reinterpret_cast<const unsigned*>(&M[e * TST + pc * 2]);
            atomic_pk_bf16(agg_bf + ((size_t)rows[e] * HD + pc * 2), pk);
        }
    }
}

// ============ node kernel ============
template <int MODE>
__global__ __launch_bounds__(256, 6) void egnn_node_mfma(
    const float* __restrict__ h, const unsigned short* __restrict__ hb,
    const float* __restrict__ pos,
    const unsigned short* __restrict__ n1t, const float* __restrict__ nb1,
    const unsigned short* __restrict__ n2t, const float* __restrict__ nb2,
    const float* __restrict__ agg_f32, const unsigned short* __restrict__ agg_bf,
    float* __restrict__ out_h, float* __restrict__ out_pos)
{
    __shared__ __align__(16) unsigned short Xn[NPB * NXST];
    __shared__ __align__(16) unsigned short Tn[NPB * TST];

    const int tid  = threadIdx.x;
    const int lane = tid & 63;
    const int w    = tid >> 6;
    const int lr   = lane & 15;
    const int lk   = (lane >> 4) * 8;
    const int c0   = w * 32;
    const int nlo  = c0 + 2 * lr;
    const int n0   = blockIdx.x * NPB;

    #pragma unroll
    for (int p = 0; p < 4; ++p) {
        const int slot  = p * 16 + (tid >> 4);
        const int pc    = tid & 15;
        const int s     = slot & 31;
        const int isagg = slot >> 5;
        int n = n0 + s; if (n >= NN) n = NN - 1;
        short8v v;
        if (MODE == 2) {
            const unsigned short* src = isagg ? (agg_bf + (size_t)n * HD)
                                              : (hb + (size_t)n * HD);
            v = *reinterpret_cast<const short8v*>(src + pc * 8);
        } else {
            const float* src = isagg ? (agg_f32 + (size_t)n * HD)
                                     : (h + (size_t)n * HD);
            float4 f0 = *reinterpret_cast<const float4*>(src + pc * 8);
            float4 f1 = *reinterpret_cast<const float4*>(src + pc * 8 + 4);
            v[0] = (short)f2bf(f0.x); v[1] = (short)f2bf(f0.y);
            v[2] = (short)f2bf(f0.z); v[3] = (short)f2bf(f0.w);
            v[4] = (short)f2bf(f1.x); v[5] = (short)f2bf(f1.y);
            v[6] = (short)f2bf(f1.z); v[7] = (short)f2bf(f1.w);
        }
        *reinterpret_cast<short8v*>(&Xn[s * NXST + isagg * 128 + pc * 8]) = v;
    }
    __syncthreads();

    f32x4 acc1[2][2] = {};
    {
        const unsigned short* xa0 = &Xn[lr * NXST + lk];
        const unsigned short* xa1 = xa0 + 16 * NXST;
        const unsigned short* wb0 = n1t + (size_t)(c0 + lr) * 256 + lk;
        const unsigned short* wb1 = wb0 + 16 * 256;
        __builtin_amdgcn_s_setprio(1);
        #pragma unroll
        for (int ks = 0; ks < 8; ++ks) {
            const int k0 = ks * 32;
            short8v a0 = *reinterpret_cast<const short8v*>(xa0 + k0);
            short8v a1 = *reinterpret_cast<const short8v*>(xa1 + k0);
            short8v b0 = *reinterpret_cast<const short8v*>(wb0 + k0);
            short8v b1 = *reinterpret_cast<const short8v*>(wb1 + k0);
            acc1[0][0] = MFMA_BF16(a0, b0, acc1[0][0]);
            acc1[0][1] = MFMA_BF16(a0, b1, acc1[0][1]);
            acc1[1][0] = MFMA_BF16(a1, b0, acc1[1][0]);
            acc1[1][1] = MFMA_BF16(a1, b1, acc1[1][1]);
        }
        __builtin_amdgcn_s_setprio(0);
    }
    {
        const float2 b1v = *reinterpret_cast<const float2*>(&nb1[nlo]);
        #pragma unroll
        for (int mt = 0; mt < 2; ++mt)
            #pragma unroll
            for (int r = 0; r < 4; ++r) {
                const int m = mt * 16 + (lane >> 4) * 4 + r;
                const unsigned pk = cvt_pk_bf16(silu(acc1[mt][0][r] + b1v.x),
                                                silu(acc1[mt][1][r] + b1v.y));
                *reinterpret_cast<unsigned*>(&Tn[m * TST + nlo]) = pk;
            }
    }
    __syncthreads();

    f32x4 acc2[2][2] = {};
    {
        const unsigned short* ta0 = &Tn[lr * TST + lk];
        const unsigned short* ta1 = ta0 + 16 * TST;
        const unsigned short* wb0 = n2t + (size_t)(c0 + lr) * 128 + lk;
        const unsigned short* wb1 = wb0 + 16 * 128;
        __builtin_amdgcn_s_setprio(1);
        #pragma unroll
        for (int ks = 0; ks < 4; ++ks) {
            const int k0 = ks * 32;
            short8v a0 = *reinterpret_cast<const short8v*>(ta0 + k0);
            short8v a1 = *reinterpret_cast<const short8v*>(ta1 + k0);
            short8v b0 = *reinterpret_cast<const short8v*>(wb0 + k0);
            short8v b1 = *reinterpret_cast<const short8v*>(wb1 + k0);
            acc2[0][0] = MFMA_BF16(a0, b0, acc2[0][0]);
            acc2[0][1] = MFMA_BF16(a0, b1, acc2[0][1]);
            acc2[1][0] = MFMA_BF16(a1, b0, acc2[1][0]);
            acc2[1][1] = MFMA_BF16(a1, b1, acc2[1][1]);
        }
        __builtin_amdgcn_s_setprio(0);
    }
    {
        const float2 b2v = *reinterpret_cast<const float2*>(&nb2[nlo]);
        #pragma unroll
        for (int mt = 0; mt < 2; ++mt)
            #pragma unroll
            for (int r = 0; r < 4; ++r) {
                const int m = mt * 16 + (lane >> 4) * 4 + r;
                const int node = n0 + m;
                if (node < NN) {
                    const size_t o = (size_t)node * HD + nlo;
                    const float2 hv = *reinterpret_cast<const float2*>(&h[o]);
                    float2 ov;
                    ov.x = hv.x + acc2[mt][0][r] + b2v.x;
                    ov.y = hv.y + acc2[mt][1][r] + b2v.y;
                    *reinterpret_cast<float2*>(&out_h[o]) = ov;
                }
            }
    }
    if (tid < NPB * 3) {
        const int s = tid / 3, a = tid % 3;
        const int node = n0 + s;
        if (node < NN) {
            const size_t idx = (size_t)node * 3 + a;
            out_pos[idx] = pos[idx] + out_pos[idx];
        }
    }
}

extern "C" void kernel_launch(void* const* d_in, const int* in_sizes, int n_in,
                              void* d_out, int out_size, void* d_ws, size_t ws_size,
                              hipStream_t stream) {
    const float* h   = (const float*)d_in[0];
    const float* pos = (const float*)d_in[1];
    const int*   ei  = (const int*)d_in[2];
    const float* mw1 = (const float*)d_in[3];
    const float* mb1 = (const float*)d_in[4];
    const float* mw2 = (const float*)d_in[5];
    const float* mb2 = (const float*)d_in[6];
    const float* cw1 = (const float*)d_in[7];
    const float* cb1 = (const float*)d_in[8];
    const float* cw2 = (const float*)d_in[9];
    const float* cb2 = (const float*)d_in[10];
    const float* nw1 = (const float*)d_in[11];
    const float* nb1 = (const float*)d_in[12];
    const float* nw2 = (const float*)d_in[13];
    const float* nb2 = (const float*)d_in[14];

    float* out     = (float*)d_out;
    float* out_h   = out;
    float* out_pos = out + (size_t)NN * HD;

    // ws layout (bf16): [wt: WTOT][hb: NN*HD][agg_bf: NN*HD]
    unsigned short* wt   = (unsigned short*)d_ws;
    unsigned short* w1t  = wt;
    unsigned short* w2t  = wt + W1T_N;
    unsigned short* n1t  = wt + W1T_N + W2T_N;
    unsigned short* n2t  = wt + W1T_N + W2T_N + N1T_N;
    unsigned short* cw1p = wt + W1T_N + W2T_N + N1T_N + N2T_N;
    unsigned short* hb   = wt + WTOT;
    unsigned short* agg_bf = hb + (size_t)NN * HD;
    const size_t need = (size_t)WTOT * 2 + 2 * (size_t)NN * HD * 2;
    const int mode2 = (ws_size >= need) ? 1 : 0;

    prep_weights<<<(WTOT + 255) / 256, 256, 0, stream>>>(mw1, mw2, nw1, nw2, cw1, wt);

    if (mode2) {
        prep_h<<<(NN * HD / 4 + 255) / 256, 256, 0, stream>>>(h, hb);
        hipMemsetAsync(agg_bf, 0, (size_t)NN * HD * 2, stream);
        hipMemsetAsync(out_pos, 0, (size_t)NN * 3 * sizeof(float), stream);
        egnn_edge_mfma<2><<<NB_E, 256, 0, stream>>>(
            h, hb, pos, ei, w1t, mb1, w2t, mb2, cw1p, cb1, cw2, cb2,
            out_h, agg_bf, out_pos);
        egnn_node_mfma<2><<<NB_N, 256, 0, stream>>>(
            h, hb, pos, n1t, nb1, n2t, nb2, out_h, agg_bf, out_h, out_pos);
    } else {
        hipMemsetAsync(d_out, 0, (size_t)out_size * sizeof(float), stream);
        egnn_edge_mfma<0><<<NB_E, 256, 0, stream>>>(
            h, hb, pos, ei, w1t, mb1, w2t, mb2, cw1p, cb1, cw2, cb2,
            out_h, agg_bf, out_pos);
        egnn_node_mfma<0><<<NB_N, 256, 0, stream>>>(
            h, hb, pos, n1t, nb1, n2t, nb2, out_h, agg_bf, out_h, out_pos);
    }
}